// Round 7
// baseline (146.229 us; speedup 1.0000x reference)
//
#include <hip/hip_runtime.h>

#define S_LEN 2048
#define D_DIM 128
#define NBH   32
#define KVB   64            // keys per kv-tile
#define QW    32            // q rows per wave
#define NW    4             // waves per block
#define QB    (QW*NW)       // 128 q rows per block
#define NQT   (S_LEN/QB)    // 16 q-tiles
#define NT    (S_LEN/KVB)   // 32 kv-tiles

typedef __attribute__((ext_vector_type(8)))  short short8;
typedef __attribute__((ext_vector_type(16))) float f32x16;

__device__ __forceinline__ unsigned f2bf_u(float f) {
  union { float f; unsigned u; } x; x.f = f;
  x.u += 0x7FFFu + ((x.u >> 16) & 1u);   // RNE
  return x.u >> 16;
}
__device__ __forceinline__ unsigned pk2(float a, float b) {
  return f2bf_u(a) | (f2bf_u(b) << 16);
}

// NOTE (R4/R5 post-mortem): cross-half reduction uses the R3-proven
// __shfl_xor(x,32); hand-rolled permlane asm for it failed twice
// (copy-coalesced self-swap; in-asm hazard). The P-path permlane asm is
// proven correct (R2/R3/R6) — operands written several instrs before use.

// fp32 -> bf16 stream converter (8 elems/thread)
__global__ __launch_bounds__(256)
void cvt_bf16(const float* __restrict__ src, unsigned* __restrict__ dst) {
  const size_t i = (size_t)blockIdx.x * 256 + threadIdx.x;
  const float4* s = (const float4*)src + i * 2;
  float4 x0 = s[0], x1 = s[1];
  uint4 u;
  u.x = pk2(x0.x, x0.y); u.y = pk2(x0.z, x0.w);
  u.z = pk2(x1.x, x1.y); u.w = pk2(x1.z, x1.w);
  ((uint4*)dst)[i] = u;
}

// Flash attention, swapped-QK^T 32x32 structure, 4 waves x 32 q-rows,
// 2 blocks/CU (independent barrier domains -> cross-block MFMA/VALU overlap).
// Score frag s = mfma32x32x16(A=K, B=Q): col(lane&31)=q (lane-local),
//   row=(r&3)+8*(r>>2)+4*hw = k. Softmax in-register, defer-max (T13).
// PV as O^T: acc[f] = mfma(A=V^T, B=P^T): col=q, row=d.
// Staging async-split (T14): LOAD = pure global loads before compute;
// STORE = repack + ds_write after compute (vmcnt wait hidden under MFMA).
template<bool PRE>
__global__ __launch_bounds__(256, 2)
void attn_fwd(const float* __restrict__ Qf, const float* __restrict__ Kf,
              const float* __restrict__ Vf,
              const unsigned short* __restrict__ Kb,
              const unsigned short* __restrict__ Vb,
              float* __restrict__ Og) {
  // K tile [k][d] bf16, byte-XOR swizzle ((row&7)<<4); double buffered (32KB)
  __shared__ __attribute__((aligned(16))) unsigned short Ks[2 * KVB * D_DIM];
  // V tile transposed [d][k] bf16, row-XOR swizzle; double buffered (32KB)
  __shared__ __attribute__((aligned(16))) unsigned short Vt[2 * D_DIM * KVB];

  const int tid  = threadIdx.x;
  const int lane = tid & 63;
  const int wid  = tid >> 6;
  const int l31  = lane & 31;
  const int hw   = lane >> 5;

  // XCD-grouped swizzle: each XCD owns 4 whole (b,h) (K+V bf16 = 4MB = L2).
  const int bid = blockIdx.x;
  const int idx = bid >> 3;
  const int bh  = (bid & 7) * 4 + (idx >> 4);
  const int qt  = idx & 15;
  const size_t base = (size_t)bh * (S_LEN * D_DIM);
  const int qrow = qt * QB + wid * QW + l31;

  // ---- Q fragments (B-operand): qb[c] elem e = Q[qrow][c*16 + hw*8 + e]
  short8 qb[8];
  {
    const float CS = 0.08838834764831845f * 1.44269504088896340f; // rsqrt(128)*log2e
    const float* qp = Qf + base + (size_t)qrow * D_DIM + hw * 8;
#pragma unroll
    for (int c = 0; c < 8; ++c) {
      float4 x0 = *(const float4*)(qp + c * 16);
      float4 x1 = *(const float4*)(qp + c * 16 + 4);
      union { unsigned u[4]; short8 v; } w;
      w.u[0] = pk2(x0.x * CS, x0.y * CS); w.u[1] = pk2(x0.z * CS, x0.w * CS);
      w.u[2] = pk2(x1.x * CS, x1.y * CS); w.u[3] = pk2(x1.z * CS, x1.w * CS);
      qb[c] = w.v;
    }
  }

  f32x16 acc[4];
#pragma unroll
  for (int f = 0; f < 4; ++f)
#pragma unroll
    for (int r = 0; r < 16; ++r) acc[f][r] = 0.f;
  float m = -3.0e38f, l = 0.f;

  // staging thread mapping (256 threads cover KVB=64 x 128 tile)
  const int kr = tid >> 2;         // K row 0..63
  const int kc = (tid & 3) << 5;   // K col shorts {0,32,64,96}
  const int vr = (tid & 15) << 2;  // V k-rows vr..vr+3
  const int vc = (tid >> 4) << 3;  // V d-cols vc..vc+7

  // raw prefetch registers (no dependent ops until STORE)
  uint4  Ku[4];                    // PRE: K bf16 raw (64B)
  uint4  Va[4];                    // PRE: V bf16 raw rows (4 x 16B)
  float4 Kq[8];                    // fallback fp32 raw
  float4 Vq[4][2];

  const unsigned short* kp = PRE ? (Kb + base + (size_t)kr * D_DIM + kc) : nullptr;
  const unsigned short* vp = PRE ? (Vb + base + (size_t)vr * D_DIM + vc) : nullptr;
  const float* kpf = PRE ? nullptr : (Kf + base + (size_t)kr * D_DIM + kc);
  const float* vpf = PRE ? nullptr : (Vf + base + (size_t)vr * D_DIM + vc);

  auto LOAD = [&]() {   // pure loads, no dependent ALU
    if constexpr (PRE) {
#pragma unroll
      for (int i = 0; i < 4; ++i) Ku[i] = *(const uint4*)(kp + 8 * i);
#pragma unroll
      for (int r = 0; r < 4; ++r) Va[r] = *(const uint4*)(vp + r * D_DIM);
      kp += (size_t)KVB * D_DIM; vp += (size_t)KVB * D_DIM;
    } else {
#pragma unroll
      for (int i = 0; i < 8; ++i) Kq[i] = *(const float4*)(kpf + 4 * i);
#pragma unroll
      for (int r = 0; r < 4; ++r) {
        Vq[r][0] = *(const float4*)(vpf + r * D_DIM);
        Vq[r][1] = *(const float4*)(vpf + r * D_DIM + 4);
      }
      kpf += (size_t)KVB * D_DIM; vpf += (size_t)KVB * D_DIM;
    }
  };

  auto STORE = [&](int p) {   // repack + LDS write (waits live here, hidden)
    uint4 kch[4];
    unsigned Vw[16];          // per d-col j: uint2 {r0|r1, r2|r3}
    if constexpr (PRE) {
#pragma unroll
      for (int i = 0; i < 4; ++i) kch[i] = Ku[i];
      union { uint4 q; unsigned u[4]; } a0, a1, a2, a3;
      a0.q = Va[0]; a1.q = Va[1]; a2.q = Va[2]; a3.q = Va[3];
#pragma unroll
      for (int j = 0; j < 8; ++j) {
        const int cmp = j >> 1, sh = (j & 1) * 16;
        const unsigned r0 = (a0.u[cmp] >> sh) & 0xFFFFu;
        const unsigned r1 = (a1.u[cmp] >> sh) & 0xFFFFu;
        const unsigned r2 = (a2.u[cmp] >> sh) & 0xFFFFu;
        const unsigned r3 = (a3.u[cmp] >> sh) & 0xFFFFu;
        Vw[2 * j]     = r0 | (r1 << 16);
        Vw[2 * j + 1] = r2 | (r3 << 16);
      }
    } else {
#pragma unroll
      for (int i = 0; i < 4; ++i) {
        kch[i].x = pk2(Kq[2*i].x, Kq[2*i].y);
        kch[i].y = pk2(Kq[2*i].z, Kq[2*i].w);
        kch[i].z = pk2(Kq[2*i+1].x, Kq[2*i+1].y);
        kch[i].w = pk2(Kq[2*i+1].z, Kq[2*i+1].w);
      }
#pragma unroll
      for (int j = 0; j < 8; ++j) {
        const float v0 = (&Vq[0][j >> 2].x)[j & 3];
        const float v1 = (&Vq[1][j >> 2].x)[j & 3];
        const float v2 = (&Vq[2][j >> 2].x)[j & 3];
        const float v3 = (&Vq[3][j >> 2].x)[j & 3];
        Vw[2 * j]     = pk2(v0, v1);
        Vw[2 * j + 1] = pk2(v2, v3);
      }
    }
    char* kdst = (char*)(Ks + p * (KVB * D_DIM));
    const int b0 = kr * 256 + kc * 2;
    const int sw = (kr & 7) << 4;
#pragma unroll
    for (int i = 0; i < 4; ++i)
      *(uint4*)(kdst + ((b0 + 16 * i) ^ sw)) = kch[i];
    char* vdst = (char*)(Vt + p * (D_DIM * KVB));
#pragma unroll
    for (int j = 0; j < 8; ++j) {
      const int d = vc + j;                 // vc%8==0 -> (d&7)==j
      const int byte = (d * 128 + vr * 2) ^ (j << 4);
      uint2 u; u.x = Vw[2 * j]; u.y = Vw[2 * j + 1];
      *(uint2*)(vdst + byte) = u;
    }
  };

  LOAD(); STORE(0); __syncthreads();
  int p = 0;
  for (int t = 0; t < NT; ++t) {
    if (t + 1 < NT) LOAD();          // issue next-tile loads (pure, async)

    const char* ksp = (const char*)(Ks + p * (KVB * D_DIM));
    const char* vtp = (const char*)(Vt + p * (D_DIM * KVB));
    const int asw = (l31 & 7) << 4;

    // ---- S^T = K Q^T (two 32-key subtiles) ----
    f32x16 s0, s1;
#pragma unroll
    for (int r = 0; r < 16; ++r) { s0[r] = 0.f; s1[r] = 0.f; }
    __builtin_amdgcn_s_setprio(1);
#pragma unroll
    for (int c = 0; c < 8; ++c) {
      const int byte = (l31 * 256 + c * 32 + hw * 16) ^ asw;
      short8 ka0 = *(const short8*)(ksp + byte);
      short8 ka1 = *(const short8*)(ksp + byte + 8192);
      s0 = __builtin_amdgcn_mfma_f32_32x32x16_bf16(ka0, qb[c], s0, 0, 0, 0);
      s1 = __builtin_amdgcn_mfma_f32_32x32x16_bf16(ka1, qb[c], s1, 0, 0, 0);
    }
    __builtin_amdgcn_s_setprio(0);

    // ---- online softmax: tree max, defer-max (T13, THR=8 log2 units) ----
    float tm[16];
#pragma unroll
    for (int r = 0; r < 16; ++r) tm[r] = fmaxf(s0[r], s1[r]);
#pragma unroll
    for (int st = 8; st > 0; st >>= 1)
#pragma unroll
      for (int r = 0; r < st; ++r) tm[r] = fmaxf(tm[r], tm[r + st]);
    const float pm = fmaxf(tm[0], __shfl_xor(tm[0], 32));
    if (!__all(pm - m <= 8.f)) {
      const float mn = fmaxf(m, pm);
      const float al = exp2f(m - mn);
      m = mn; l *= al;
#pragma unroll
      for (int f = 0; f < 4; ++f)
#pragma unroll
        for (int r = 0; r < 16; ++r) acc[f][r] *= al;
    }
    float ts[16];
#pragma unroll
    for (int r = 0; r < 16; ++r) {
      s0[r] = exp2f(s0[r] - m);
      s1[r] = exp2f(s1[r] - m);
      ts[r] = s0[r] + s1[r];
    }
#pragma unroll
    for (int st = 8; st > 0; st >>= 1)
#pragma unroll
      for (int r = 0; r < st; ++r) ts[r] += ts[r + st];
    l += ts[0] + __shfl_xor(ts[0], 32);

    // ---- P^T -> bf16 B-frags (cvt_pk + permlane32_swap); O^T += V^T P^T ----
    // pb elem e (k = 16*t2 + 8*hw + e) comes from score reg (e&3)+8*(t2&1)+4*hw
    // of s0 (t2<2) / s1 (t2>=2), source lane-half e>>2 (permlane32_swap).
#pragma unroll
    for (int t2 = 0; t2 < 4; ++t2) {
      unsigned w0, w1, w2, w3;
      if (t2 < 2) {
        const int rb = 8 * t2;
        asm("v_cvt_pk_bf16_f32 %0, %1, %2" : "=v"(w0) : "v"(s0[rb+0]), "v"(s0[rb+1]));
        asm("v_cvt_pk_bf16_f32 %0, %1, %2" : "=v"(w1) : "v"(s0[rb+2]), "v"(s0[rb+3]));
        asm("v_cvt_pk_bf16_f32 %0, %1, %2" : "=v"(w2) : "v"(s0[rb+4]), "v"(s0[rb+5]));
        asm("v_cvt_pk_bf16_f32 %0, %1, %2" : "=v"(w3) : "v"(s0[rb+6]), "v"(s0[rb+7]));
      } else {
        const int rb = 8 * (t2 - 2);
        asm("v_cvt_pk_bf16_f32 %0, %1, %2" : "=v"(w0) : "v"(s1[rb+0]), "v"(s1[rb+1]));
        asm("v_cvt_pk_bf16_f32 %0, %1, %2" : "=v"(w1) : "v"(s1[rb+2]), "v"(s1[rb+3]));
        asm("v_cvt_pk_bf16_f32 %0, %1, %2" : "=v"(w2) : "v"(s1[rb+4]), "v"(s1[rb+5]));
        asm("v_cvt_pk_bf16_f32 %0, %1, %2" : "=v"(w3) : "v"(s1[rb+6]), "v"(s1[rb+7]));
      }
      asm("v_permlane32_swap_b32 %0, %1" : "+v"(w0), "+v"(w2));
      asm("v_permlane32_swap_b32 %0, %1" : "+v"(w1), "+v"(w3));
      union { unsigned u[4]; short8 v; } pb;
      pb.u[0] = w0; pb.u[1] = w1; pb.u[2] = w2; pb.u[3] = w3;
      __builtin_amdgcn_s_setprio(1);
#pragma unroll
      for (int f = 0; f < 4; ++f) {
        const int byte = ((32 * f + l31) * 128 + t2 * 32 + hw * 16) ^ asw;
        short8 va = *(const short8*)(vtp + byte);
        acc[f] = __builtin_amdgcn_mfma_f32_32x32x16_bf16(va, pb.v, acc[f], 0, 0, 0);
      }
      __builtin_amdgcn_s_setprio(0);
    }

    if (t + 1 < NT) STORE(p ^ 1);    // vmcnt wait lands here, hidden
    __syncthreads();
    p ^= 1;
  }

  // ---- epilogue: O[q][d] = acc^T / l  (d = 32f + 8g + 4hw + j) ----
  const float inv = 1.0f / l;
  float* op = Og + base + (size_t)qrow * D_DIM;
#pragma unroll
  for (int f = 0; f < 4; ++f)
#pragma unroll
    for (int g = 0; g < 4; ++g) {
      float4 o;
      o.x = acc[f][4*g+0] * inv; o.y = acc[f][4*g+1] * inv;
      o.z = acc[f][4*g+2] * inv; o.w = acc[f][4*g+3] * inv;
      *(float4*)(op + 32 * f + 8 * g + 4 * hw) = o;
    }
}

extern "C" void kernel_launch(void* const* d_in, const int* in_sizes, int n_in,
                              void* d_out, int out_size, void* d_ws, size_t ws_size,
                              hipStream_t stream) {
  const float* q = (const float*)d_in[0];
  const float* k = (const float*)d_in[1];
  const float* v = (const float*)d_in[2];
  float* out = (float*)d_out;
  const size_t nel = (size_t)NBH * S_LEN * D_DIM;          // 8,388,608
  const size_t need = 2 * nel * sizeof(unsigned short);    // 32 MiB
  const int grid = NBH * NQT;                              // 512
  if (ws_size >= need) {
    unsigned short* kb = (unsigned short*)d_ws;
    unsigned short* vb = kb + nel;
    const int cgrid = (int)(nel / 8 / 256);                // 4096
    cvt_bf16<<<cgrid, 256, 0, stream>>>(k, (unsigned*)kb);
    cvt_bf16<<<cgrid, 256, 0, stream>>>(v, (unsigned*)vb);
    attn_fwd<true><<<grid, 256, 0, stream>>>(q, k, v, kb, vb, out);
  } else {
    attn_fwd<false><<<grid, 256, 0, stream>>>(q, k, v, nullptr, nullptr, out);
  }
}